// Round 6
// baseline (217.997 us; speedup 1.0000x reference)
//
#include <hip/hip_runtime.h>
#include <hip/hip_bf16.h>
#include <stdint.h>

#define NN 8192
#define GG 512
#define HH 512
#define LL 64
#define TOPK 9                 // K+1 = 9 (incl. self, self weight zeroed)
#define NEDGE (NN*TOPK)        // 73728 directed edges
#define NNZ (2*NEDGE)          // 147456 CSR entries after symmetrization
#define GRES 32                // spatial grid resolution (cell = 1/32)
#define NCELL (GRES*GRES)
#define BPAD 516               // LDS B-panel row pad: 258 dwords == 2 mod 32 (conflict-free class)

typedef unsigned long long u64;
typedef unsigned int u32;
typedef unsigned short u16;

using bf16x8 = __attribute__((ext_vector_type(8))) short;
using f32x4  = __attribute__((ext_vector_type(4))) float;

struct InPtrs { const void* p[12]; };

__device__ __forceinline__ float bf2f(u16 u) { return __uint_as_float(((u32)u) << 16); }
__device__ __forceinline__ u16 f2bf(float f) {
  u32 x = __float_as_uint(f);
  u32 r = x + 0x7fffu + ((x >> 16) & 1u);   // RNE
  return (u16)(r >> 16);
}

// ---------------- inline dtype detection (wave 0 samples 64 u16s of coords) ----------------
__device__ __forceinline__ int detect_isbf(const void* coords_raw, int tid, int* sh) {
  if (tid < 64) {
    float v = bf2f(((const u16*)coords_raw)[tid]);
    bool bad = !(v >= -0.01f && v <= 1.02f);
    u64 bb = __ballot(bad);
    if (tid == 0) *sh = (bb == 0ULL) ? 1 : 0;
  }
  __syncthreads();
  return *sh;
}

// ---------------- convert: small f32 tensors + VECTORIZED big weights + gene ----------------
// fp32 world (live path): float4 loads -> packed 4xbf16 u64 stores (4x fewer mem ops than
// the old scalar 11-way-branch loop). bf16 world: uint4 passthrough copies.
__global__ void k_conv_small(InPtrs in, int* __restrict__ flag,
                             float* __restrict__ f32blk, u16* __restrict__ bfblk,
                             float* __restrict__ deg, int* __restrict__ cnt,
                             float* __restrict__ sq, u32* __restrict__ geneB) {
  __shared__ int sh;
  int tid = threadIdx.x;
  int isbf = detect_isbf(in.p[1], tid, &sh);
  int gtid = blockIdx.x * blockDim.x + tid;
  int gsz = gridDim.x * blockDim.x;
  if (gtid == 0) *flag = isbf;
  if (gtid < NN) {
    deg[gtid] = 0.0f;
    float x, y;
    if (isbf) { x = bf2f(((const u16*)in.p[1])[2 * gtid]); y = bf2f(((const u16*)in.p[1])[2 * gtid + 1]); }
    else      { x = ((const float*)in.p[1])[2 * gtid];     y = ((const float*)in.p[1])[2 * gtid + 1]; }
    sq[gtid] = __fadd_rn(__fmul_rn(x, x), __fmul_rn(y, y));
  } else if (gtid < 2 * NN) {
    cnt[gtid - NN] = 0;
  }

  // small f32-dest tensors (both worlds): coords, b_g1, W_c1, b_c1, b_msg, b_self, b_z
  {
    const int scnt[7] = {16384, 512, 1024, 512, 512, 512, 64};
    const int sidx[7] = {1, 3, 4, 5, 7, 9, 11};
    const int sdof[7] = {0, 16384, 16896, 17920, 18432, 18944, 19456};
    for (int e = gtid; e < 19520; e += gsz) {
      int base = 0;
#pragma unroll
      for (int s = 0; s < 7; ++s) {
        if (e < base + scnt[s]) {
          int loc = e - base;
          const void* src = in.p[sidx[s]];
          f32blk[sdof[s] + loc] = isbf ? bf2f(((const u16*)src)[loc]) : ((const float*)src)[loc];
          break;
        }
        base += scnt[s];
      }
    }
  }

  if (!isbf) {
    // big weights f32 -> bf16: Wg(262144), Wm(262144), Ws(262144), Wz(32768) = 204800 float4s
    for (int v = gtid; v < 204800; v += gsz) {
      const float4* sp; u16* dp; int loc;
      if (v < 65536)       { sp = (const float4*)in.p[2];  dp = bfblk;          loc = v; }
      else if (v < 131072) { sp = (const float4*)in.p[6];  dp = bfblk + 262144; loc = v - 65536; }
      else if (v < 196608) { sp = (const float4*)in.p[8];  dp = bfblk + 524288; loc = v - 131072; }
      else                 { sp = (const float4*)in.p[10]; dp = bfblk + 786432; loc = v - 196608; }
      float4 f = sp[loc];
      u64 pk = (u64)f2bf(f.x) | ((u64)f2bf(f.y) << 16) | ((u64)f2bf(f.z) << 32) | ((u64)f2bf(f.w) << 48);
      *(u64*)(dp + 4 * loc) = pk;
    }
    // gene f32 -> bf16: 1048576 float4s
    const float4* g4 = (const float4*)in.p[0];
    u64* gd = (u64*)geneB;
    for (int v = gtid; v < NN * GG / 4; v += gsz) {
      float4 f = g4[v];
      gd[v] = (u64)f2bf(f.x) | ((u64)f2bf(f.y) << 16) | ((u64)f2bf(f.z) << 32) | ((u64)f2bf(f.w) << 48);
    }
  } else {
    // bf16 passthrough copies: 102400 uint4 chunks (gene copy skipped; bgemm0 reads raw)
    for (int v = gtid; v < 102400; v += gsz) {
      const uint4* sp; uint4* dp; int loc;
      if (v < 32768)      { sp = (const uint4*)in.p[2];  dp = (uint4*)bfblk;            loc = v; }
      else if (v < 65536) { sp = (const uint4*)in.p[6];  dp = (uint4*)(bfblk + 262144); loc = v - 32768; }
      else if (v < 98304) { sp = (const uint4*)in.p[8];  dp = (uint4*)(bfblk + 524288); loc = v - 65536; }
      else                { sp = (const uint4*)in.p[10]; dp = (uint4*)(bfblk + 786432); loc = v - 98304; }
      dp[loc] = sp[loc];
    }
  }
}

__device__ __forceinline__ int cell_of(float v) {
  int c = (int)(v * (float)GRES);
  return c < 0 ? 0 : (c > GRES - 1 ? GRES - 1 : c);
}

// ---------------- grid histogram + scan + fill (single block; coords stashed in regs) ------
__global__ __launch_bounds__(1024) void k_grid(const float* __restrict__ coords,
                                               int* __restrict__ gstart,
                                               float4* __restrict__ pts) {
  __shared__ int hist[NCELL];
  __shared__ int part[NCELL];
  int t = threadIdx.x;
  hist[t] = 0;
  __syncthreads();
  float xs[8], ys[8]; int cl[8];
#pragma unroll
  for (int q = 0; q < 8; ++q) {
    int i = t + 1024 * q;
    float2 c = ((const float2*)coords)[i];
    xs[q] = c.x; ys[q] = c.y;
    cl[q] = cell_of(c.y) * GRES + cell_of(c.x);
    atomicAdd(&hist[cl[q]], 1);
  }
  __syncthreads();
  int v = hist[t];
  part[t] = v;
  __syncthreads();
  for (int o = 1; o < NCELL; o <<= 1) {
    int add = 0;
    if (t >= o) add = part[t - o];
    __syncthreads();
    part[t] += add;
    __syncthreads();
  }
  int excl = part[t] - v;
  gstart[t] = excl;
  hist[t] = excl;                 // reuse hist as the fill cursor (LDS atomics)
  if (t == NCELL - 1) gstart[NCELL] = part[t];
  __syncthreads();
#pragma unroll
  for (int q = 0; q < 8; ++q) {
    int i = t + 1024 * q;
    int p = atomicAdd(&hist[cl[q]], 1);
    // z = x*x + y*y with the SAME rounding sequence conv_small used for sq[i] -> bit-identical
    float z = __fadd_rn(__fmul_rn(xs[q], xs[q]), __fmul_rn(ys[q], ys[q]));
    pts[p] = make_float4(xs[q], ys[q], z, __int_as_float(i));
  }
}

// ---------------- KNN top-9: adaptive window (3x3 -> 5x5 -> full), EXACT u64 keys ----------
// A point outside the (2r+1)^2 cell window is > r*h away (h=1/32 cell). So the window is
// provably sufficient iff computed d9^2 < (r*h)^2 (conservative margin for fp error).
// ~88% of queries resolve at 3x3 (~72 candidate pts vs 200 at 5x5); edge nodes escalate.
// Escalation is wave-uniform (d9 from a full-wave reduction). Comparator stays EXACT
// (round-4 lesson: truncated comparators swap rank-9 neighbors -> O(1) output error).
__device__ __forceinline__ float knn_pass(const float4* __restrict__ pts,
                                          const int* __restrict__ gstart,
                                          int x0, int x1, int y0, int y1,
                                          float qx, float qy, float sqi, int lane,
                                          u64 (&karr)[TOPK]) {
  u64 a0 = ~0ULL, a1 = ~0ULL, a2 = ~0ULL, a3 = ~0ULL, a4 = ~0ULL,
      a5 = ~0ULL, a6 = ~0ULL, a7 = ~0ULL, a8 = ~0ULL;
#define KSTEP(A) { u64 t_ = A; bool p_ = x < t_; A = p_ ? x : t_; x = p_ ? t_ : x; }
  for (int yy = y0; yy <= y1; ++yy) {
    int sbeg = gstart[yy * GRES + x0];
    int send = gstart[yy * GRES + x1 + 1];
    for (int p = sbeg + lane; p < send; p += 64) {
      float4 pt = pts[p];
      float dot = __fmaf_rn(qy, pt.y, __fmul_rn(qx, pt.x));
      float d2  = fmaxf(__fsub_rn(__fadd_rn(sqi, pt.z), __fmul_rn(2.0f, dot)), 0.0f);
      u64 x = ((u64)__float_as_uint(d2) << 32) | (u32)__float_as_int(pt.w);
      KSTEP(a0) KSTEP(a1) KSTEP(a2) KSTEP(a3) KSTEP(a4)
      KSTEP(a5) KSTEP(a6) KSTEP(a7) KSTEP(a8)
    }
  }
#undef KSTEP
#pragma unroll
  for (int r = 0; r < TOPK; ++r) {
    u64 g = a0;
#pragma unroll
    for (int o = 32; o > 0; o >>= 1) {
      u64 other = __shfl_xor(g, o, 64);
      if (other < g) g = other;
    }
    bool own = (a0 == g);
    a0 = own ? a1 : a0;  a1 = own ? a2 : a1;  a2 = own ? a3 : a2;
    a3 = own ? a4 : a3;  a4 = own ? a5 : a4;  a5 = own ? a6 : a5;
    a6 = own ? a7 : a6;  a7 = own ? a8 : a7;  a8 = own ? ~0ULL : a8;
    karr[r] = g;
  }
  return __uint_as_float((u32)(karr[TOPK - 1] >> 32));
}

__global__ __launch_bounds__(256) void k_knn_grid(const float4* __restrict__ pts,
                                                  const int* __restrict__ gstart,
                                                  const float* __restrict__ coords,
                                                  const float* __restrict__ sq,
                                                  int* __restrict__ eidx, float* __restrict__ ew,
                                                  float* __restrict__ deg, int* __restrict__ cnt) {
  const int w = threadIdx.x >> 6, lane = threadIdx.x & 63;
  const int i = blockIdx.x * 4 + w;
  const float qx = coords[2 * i], qy = coords[2 * i + 1];
  const float sqi = sq[i];
  const int cx = cell_of(qx), cy = cell_of(qy);

  u64 karr[TOPK];
  float d9 = knn_pass(pts, gstart, max(cx - 1, 0), min(cx + 1, GRES - 1),
                      max(cy - 1, 0), min(cy + 1, GRES - 1), qx, qy, sqi, lane, karr);
  if (!(d9 < 0.00097f)) {                       // h^2 = 0.0009766, 0.7% margin
    d9 = knn_pass(pts, gstart, max(cx - 2, 0), min(cx + 2, GRES - 1),
                  max(cy - 2, 0), min(cy + 2, GRES - 1), qx, qy, sqi, lane, karr);
    if (!(d9 < 0.0038937f))                     // (2h)^2 = 0.0039063
      knn_pass(pts, gstart, 0, GRES - 1, 0, GRES - 1, qx, qy, sqi, lane, karr);
  }

  // emission: lanes 0..8 in parallel (karr is wave-uniform; compile-time-index select)
  if (lane < TOPK) {
    u64 g = karr[0];
#pragma unroll
    for (int r = 1; r < TOPK; ++r) g = (lane == r) ? karr[r] : g;
    int j = (int)(g & 0xffffffffu);
    float d2 = __uint_as_float((u32)(g >> 32));
    float wgt = (j == i) ? 0.0f : expf(-0.5f * d2);
    eidx[i * TOPK + lane] = j;
    ew[i * TOPK + lane] = wgt;
    float h = 0.5f * wgt;
    atomicAdd(&deg[j], h);
    atomicAdd(&cnt[j], 1);
    atomicAdd(&deg[i], h);     // 9 same-address adds; cnt[i] coalesces to one wave-add
    atomicAdd(&cnt[i], 1);
  }
}

// ---------------- CSR scan (+ dis from deg) ----------------
__global__ __launch_bounds__(1024) void k_scan(const int* __restrict__ cnt,
                                               const float* __restrict__ deg,
                                               int* __restrict__ rs, int* __restrict__ cur,
                                               float* __restrict__ dis) {
  __shared__ int part[1024];
  int t = threadIdx.x;
  int base = t * 8;
  int loc[8]; int s = 0;
#pragma unroll
  for (int q = 0; q < 8; ++q) { loc[q] = s; s += cnt[base + q]; }
  part[t] = s;
  __syncthreads();
  for (int o = 1; o < 1024; o <<= 1) {
    int v = 0;
    if (t >= o) v = part[t - o];
    __syncthreads();
    part[t] += v;
    __syncthreads();
  }
  int excl = (t == 0) ? 0 : part[t - 1];
#pragma unroll
  for (int q = 0; q < 8; ++q) {
    int val = excl + loc[q];
    rs[base + q] = val;
    cur[base + q] = val;
    dis[base + q] = 1.0f / sqrtf(deg[base + q] + 1e-8f);
  }
  if (t == 1023) rs[NN] = excl + s;
}

__global__ void k_fill(const int* __restrict__ eidx, const float* __restrict__ ew,
                       int* __restrict__ cur, int* __restrict__ ccol, float* __restrict__ cw) {
  int t = blockIdx.x * blockDim.x + threadIdx.x;
  if (t >= NEDGE) return;
  int i = t / TOPK;
  int j = eidx[t] & (NN - 1);
  float h = 0.5f * ew[t];
  int s1 = atomicAdd(&cur[i], 1); ccol[s1] = j; cw[s1] = h;
  int s2 = atomicAdd(&cur[j], 1); ccol[s2] = i; cw[s2] = h;
}

// ====================================================================================
// B-stationary barrier-free MFMA GEMMs (see round-2 notes).
// ====================================================================================

// ---- GEMM1: h = relu(gene@Wg^T + b) + relu(coords-MLP).  512 thr, BM=128, grid (64,8) ----
__global__ __launch_bounds__(512, 4) void k_bgemm0(const void* __restrict__ Araw,
                                                   const u16* __restrict__ Aconv,
                                                   const u16* __restrict__ W,
                                                   const float* __restrict__ bias,
                                                   const float* __restrict__ coords,
                                                   const float* __restrict__ Wc1,
                                                   const float* __restrict__ bc1,
                                                   const int* __restrict__ flag,
                                                   u16* __restrict__ outp) {
  __shared__ u16 Bs[64][BPAD];
  const int tid = threadIdx.x, lane = tid & 63, w = tid >> 6;
  const int quad = lane >> 4, l16 = lane & 15;
  const int row0 = blockIdx.x * 128, col0 = blockIdx.y * 64;
  int flg = *flag;
  const u16* A = flg ? (const u16*)Araw : Aconv;

  // stage B panel: 64 rows x 64 chunks of 8 u16
#pragma unroll
  for (int q = 0; q < 8; ++q) {
    int idx = tid + 512 * q;
    int r = idx >> 6, c = idx & 63;
    *(uint4*)(&Bs[r][c * 8]) = *(const uint4*)(W + (size_t)(col0 + r) * 512 + c * 8);
  }
  __syncthreads();

  f32x4 acc[4];
#pragma unroll
  for (int n = 0; n < 4; ++n) acc[n] = (f32x4){0.f, 0.f, 0.f, 0.f};

  const u16* Ab = A + (size_t)(row0 + w * 16 + l16) * 512 + quad * 8;
#pragma unroll
  for (int kc = 0; kc < 16; ++kc) {
    bf16x8 af = *(const bf16x8*)(Ab + kc * 32);
    bf16x8 bfr[4];
#pragma unroll
    for (int n = 0; n < 4; ++n)
      bfr[n] = *(const bf16x8*)(&Bs[n * 16 + l16][kc * 32 + quad * 8]);
#pragma unroll
    for (int n = 0; n < 4; ++n)
      acc[n] = __builtin_amdgcn_mfma_f32_16x16x32_bf16(af, bfr[n], acc[n], 0, 0, 0);
  }

  __syncthreads();                 // all waves done reading Bs -> reuse as staging tile
  u16* St = &Bs[0][0];             // [128][64]
  {
    int rloc = w * 16 + quad * 4;
    int rbase = row0 + rloc;
    float cx[4], cy[4];
#pragma unroll
    for (int reg = 0; reg < 4; ++reg) { cx[reg] = coords[2 * (rbase + reg)]; cy[reg] = coords[2 * (rbase + reg) + 1]; }
#pragma unroll
    for (int n = 0; n < 4; ++n) {
      int cg = col0 + n * 16 + l16;
      float bval = bias[cg];
      float wc0 = Wc1[2 * cg], wc1 = Wc1[2 * cg + 1], bcv = bc1[cg];
#pragma unroll
      for (int reg = 0; reg < 4; ++reg) {
        float v = acc[n][reg] + bval;
        float hc = cx[reg] * wc0 + cy[reg] * wc1 + bcv;
        v = fmaxf(v, 0.f) + fmaxf(hc, 0.f);
        St[(rloc + reg) * 64 + n * 16 + l16] = f2bf(v);
      }
    }
  }
  __syncthreads();
#pragma unroll
  for (int q = 0; q < 2; ++q) {
    int idx = tid + 512 * q;
    int r = idx >> 3, c = idx & 7;
    *(uint4*)(outp + (size_t)(row0 + r) * 512 + col0 + c * 8) = ((const uint4*)St)[idx];
  }
}

// ---- dual GEMM: hm = h@Wm^T (raw), hs = relu(h@Ws^T + b_self). Wcat = [Wm;Ws] 1024 rows ----
__global__ __launch_bounds__(512, 4) void k_bgemm_dual(const u16* __restrict__ A,
                                                       const u16* __restrict__ Wcat,
                                                       const float* __restrict__ bself,
                                                       u16* __restrict__ hm,
                                                       u16* __restrict__ hs) {
  __shared__ u16 Bs[64][BPAD];
  const int tid = threadIdx.x, lane = tid & 63, w = tid >> 6;
  const int quad = lane >> 4, l16 = lane & 15;
  const int row0 = blockIdx.x * 256, col0 = blockIdx.y * 64;   // col0 in [0,1024)
  const int selfhalf = (col0 >= 512);

#pragma unroll
  for (int q = 0; q < 8; ++q) {
    int idx = tid + 512 * q;
    int r = idx >> 6, c = idx & 63;
    *(uint4*)(&Bs[r][c * 8]) = *(const uint4*)(Wcat + (size_t)(col0 + r) * 512 + c * 8);
  }
  __syncthreads();

  f32x4 acc[2][4];
#pragma unroll
  for (int mr = 0; mr < 2; ++mr)
#pragma unroll
    for (int n = 0; n < 4; ++n) acc[mr][n] = (f32x4){0.f, 0.f, 0.f, 0.f};

  const u16* Ab = A + (size_t)(row0 + w * 32 + l16) * 512 + quad * 8;
#pragma unroll
  for (int kc = 0; kc < 16; ++kc) {
    bf16x8 af0 = *(const bf16x8*)(Ab + kc * 32);
    bf16x8 af1 = *(const bf16x8*)(Ab + 16 * 512 + kc * 32);
    bf16x8 bfr[4];
#pragma unroll
    for (int n = 0; n < 4; ++n)
      bfr[n] = *(const bf16x8*)(&Bs[n * 16 + l16][kc * 32 + quad * 8]);
#pragma unroll
    for (int n = 0; n < 4; ++n) {
      acc[0][n] = __builtin_amdgcn_mfma_f32_16x16x32_bf16(af0, bfr[n], acc[0][n], 0, 0, 0);
      acc[1][n] = __builtin_amdgcn_mfma_f32_16x16x32_bf16(af1, bfr[n], acc[1][n], 0, 0, 0);
    }
  }

  __syncthreads();
  u16* St = &Bs[0][0];             // [256][64]
  const int dcol0 = col0 & 511;
#pragma unroll
  for (int mr = 0; mr < 2; ++mr) {
    int rloc = w * 32 + mr * 16 + quad * 4;
#pragma unroll
    for (int n = 0; n < 4; ++n) {
      int cl = dcol0 + n * 16 + l16;
      float bval = selfhalf ? bself[cl] : 0.f;
#pragma unroll
      for (int reg = 0; reg < 4; ++reg) {
        float v = acc[mr][n][reg];
        if (selfhalf) v = fmaxf(v + bval, 0.f);   // hs = relu(h@Ws^T + b_self)
        St[(rloc + reg) * 64 + n * 16 + l16] = f2bf(v);  // hm raw: bias added post-agg
      }
    }
  }
  __syncthreads();
  u16* dst = selfhalf ? hs : hm;
#pragma unroll
  for (int q = 0; q < 4; ++q) {
    int idx = tid + 512 * q;
    int r = idx >> 3, c = idx & 7;
    *(uint4*)(dst + (size_t)(row0 + r) * 512 + dcol0 + c * 8) = ((const uint4*)St)[idx];
  }
}

// ---- h_final = relu(relu(A_norm@hm + b_msg) + hs)  (SpMV, 4-edge-wide gather) ----
__global__ __launch_bounds__(256) void k_agg2(const int* __restrict__ rs, const int* __restrict__ ccol,
                                              const float* __restrict__ cw, const float* __restrict__ dis,
                                              const u16* __restrict__ hm, const u16* __restrict__ hs,
                                              const float* __restrict__ bmsg, u16* __restrict__ hf) {
  __shared__ float sacc[4][512];
  const int i = blockIdx.x, t = threadIdx.x;
  const int g = t >> 6, l = t & 63;
  const int b = rs[i], e = rs[i + 1];
  float acc[8];
#pragma unroll
  for (int j = 0; j < 8; ++j) acc[j] = 0.f;
  for (int q = b + g; q < e; q += 4) {
    int c = ccol[q];
    float w = cw[q] * dis[c];
    uint4 p = *(const uint4*)(hm + (size_t)c * HH + l * 8);
    acc[0] = fmaf(w, bf2f((u16)(p.x & 0xffff)), acc[0]);
    acc[1] = fmaf(w, bf2f((u16)(p.x >> 16)),    acc[1]);
    acc[2] = fmaf(w, bf2f((u16)(p.y & 0xffff)), acc[2]);
    acc[3] = fmaf(w, bf2f((u16)(p.y >> 16)),    acc[3]);
    acc[4] = fmaf(w, bf2f((u16)(p.z & 0xffff)), acc[4]);
    acc[5] = fmaf(w, bf2f((u16)(p.z >> 16)),    acc[5]);
    acc[6] = fmaf(w, bf2f((u16)(p.w & 0xffff)), acc[6]);
    acc[7] = fmaf(w, bf2f((u16)(p.w >> 16)),    acc[7]);
  }
#pragma unroll
  for (int j = 0; j < 8; ++j) sacc[g][l * 8 + j] = acc[j];
  __syncthreads();
  float di = dis[i];
  int c0 = 2 * t, c1 = 2 * t + 1;
  float s0 = (sacc[0][c0] + sacc[1][c0]) + (sacc[2][c0] + sacc[3][c0]);
  float s1 = (sacc[0][c1] + sacc[1][c1]) + (sacc[2][c1] + sacc[3][c1]);
  float m0 = fmaxf(fmaf(di, s0, bmsg[c0]), 0.f);
  float m1 = fmaxf(fmaf(di, s1, bmsg[c1]), 0.f);
  u32 sp = *(const u32*)(hs + (size_t)i * HH + c0);
  float f0 = fmaxf(m0 + bf2f((u16)(sp & 0xffff)), 0.f);
  float f1 = fmaxf(m1 + bf2f((u16)(sp >> 16)), 0.f);
  u32 packed = (u32)f2bf(f0) | ((u32)f2bf(f1) << 16);
  *(u32*)(hf + (size_t)i * HH + c0) = packed;
}

// ---- GEMM3: out = h_final@Wz^T + bz.  BM=16, 256 thr, grid 512; LDS-staged stores ----
__global__ __launch_bounds__(256) void k_bgemm3(const u16* __restrict__ A,
                                                const u16* __restrict__ W,
                                                const float* __restrict__ bias,
                                                const int* __restrict__ flag,
                                                void* __restrict__ outp) {
  __shared__ u16 Bs[64][BPAD];
  const int tid = threadIdx.x, lane = tid & 63, w = tid >> 6;   // w = n-frag 0..3
  const int quad = lane >> 4, l16 = lane & 15;
  const int row0 = blockIdx.x * 16;
  int flg = *flag;

#pragma unroll
  for (int q = 0; q < 16; ++q) {
    int idx = tid + 256 * q;
    int r = idx >> 6, c = idx & 63;
    *(uint4*)(&Bs[r][c * 8]) = *(const uint4*)(W + (size_t)r * 512 + c * 8);
  }
  __syncthreads();

  f32x4 acc = (f32x4){0.f, 0.f, 0.f, 0.f};
  const u16* Ab = A + (size_t)(row0 + l16) * 512 + quad * 8;
#pragma unroll
  for (int kc = 0; kc < 16; ++kc) {
    bf16x8 af  = *(const bf16x8*)(Ab + kc * 32);
    bf16x8 bfw = *(const bf16x8*)(&Bs[w * 16 + l16][kc * 32 + quad * 8]);
    acc = __builtin_amdgcn_mfma_f32_16x16x32_bf16(af, bfw, acc, 0, 0, 0);
  }

  __syncthreads();
  if (!flg) {
    // fp32-output world (live path): stage [16][64] f32 tile, float4 stores
    float* Stf = (float*)&Bs[0][0];
    float bval = bias[w * 16 + l16];
#pragma unroll
    for (int reg = 0; reg < 4; ++reg)
      Stf[(quad * 4 + reg) * 64 + w * 16 + l16] = acc[reg] + bval;
    __syncthreads();
    int r = tid >> 4, c = tid & 15;
    ((float4*)outp)[(size_t)(row0 + r) * 16 + c] = ((const float4*)Stf)[tid];
    return;
  }

  u16* St = &Bs[0][0];             // [16][64] bf16
  float bval = bias[w * 16 + l16];
#pragma unroll
  for (int reg = 0; reg < 4; ++reg)
    St[(quad * 4 + reg) * 64 + w * 16 + l16] = f2bf(acc[reg] + bval);
  __syncthreads();
  if (tid < 128) {
    int r = tid >> 3, c = tid & 7;
    *(uint4*)((u16*)outp + (size_t)(row0 + r) * 64 + c * 8) = ((const uint4*)St)[tid];
  }
}

extern "C" void kernel_launch(void* const* d_in, const int* in_sizes, int n_in,
                              void* d_out, int out_size, void* d_ws, size_t ws_size,
                              hipStream_t stream) {
  float* ws = (float*)d_ws;
  size_t off = 0;
  auto alloc = [&](size_t n) { size_t o = off; off += (n + 15) & ~(size_t)15; return o; };

  const size_t PLANE = (size_t)NN * HH / 2;

  size_t o_flag  = alloc(16);
  size_t o_f32   = alloc(19520);
  size_t o_bfw   = alloc(409600);
  size_t o_geneB = alloc(PLANE);
  size_t o_Hb    = alloc(PLANE);
  size_t o_Mb    = alloc(PLANE);
  size_t o_sq    = alloc(NN);
  size_t o_deg   = alloc(NN);
  size_t o_dis   = alloc(NN);
  size_t o_cnt   = alloc(NN);
  size_t o_rs    = alloc(NN + 16);
  size_t o_cur   = alloc(NN);
  size_t o_eidx  = alloc(NEDGE);
  size_t o_ew    = alloc(NEDGE);
  size_t o_ccol  = alloc(NNZ);
  size_t o_cw    = alloc(NNZ);
  size_t o_pts   = alloc(NN * 4);
  size_t o_gsta  = alloc(NCELL + 16);
  (void)ws_size;

  int*   flag    = (int*)(ws + o_flag);
  float* f32blk  = ws + o_f32;
  float* coordsF = f32blk + 0;
  float* bg1     = f32blk + 16384;
  float* Wc1f    = f32blk + 16896;
  float* bc1f    = f32blk + 17920;
  float* bmsg    = f32blk + 18432;
  float* bself   = f32blk + 18944;
  float* bz      = f32blk + 19456;
  u16*   bfblk   = (u16*)(ws + o_bfw);
  u16*   WgB     = bfblk + 0;
  u16*   WmB     = bfblk + 262144;   // [Wm;Ws] contiguous 1024x512 starting here
  u16*   WzB     = bfblk + 786432;
  u16*   geneB   = (u16*)(ws + o_geneB);
  u16*   Hb      = (u16*)(ws + o_Hb);
  u16*   Mb      = (u16*)(ws + o_Mb);
  float* sq      = ws + o_sq;
  float* deg     = ws + o_deg;
  float* dis     = ws + o_dis;
  int*   cnt     = (int*)(ws + o_cnt);
  int*   rs      = (int*)(ws + o_rs);
  int*   cur     = (int*)(ws + o_cur);
  int*   eidx    = (int*)(ws + o_eidx);
  float* ew      = ws + o_ew;
  int*   ccol    = (int*)(ws + o_ccol);
  float* cw      = ws + o_cw;
  float4* pts    = (float4*)(ws + o_pts);
  int*   gstart  = (int*)(ws + o_gsta);

  // plane reuse: hm <- geneB plane; hs <- Mb plane; h_final <- Hb plane.
  u16* HM = geneB;
  u16* HS = Mb;
  u16* HF = Hb;

  InPtrs ip;
  for (int s = 0; s < 12; ++s) ip.p[s] = d_in[s];

  k_conv_small<<<512, 256, 0, stream>>>(ip, flag, f32blk, bfblk, deg, cnt, sq, (u32*)geneB);
  // bgemm0 right after conv: geneB still L2-warm; graph kernels don't need Hb
  k_bgemm0<<<dim3(64, 8), 512, 0, stream>>>(d_in[0], geneB, WgB, bg1, coordsF, Wc1f, bc1f, flag, Hb);
  k_grid<<<1, 1024, 0, stream>>>(coordsF, gstart, pts);
  k_knn_grid<<<NN / 4, 256, 0, stream>>>(pts, gstart, coordsF, sq, eidx, ew, deg, cnt);
  k_scan<<<1, 1024, 0, stream>>>(cnt, deg, rs, cur, dis);
  k_fill<<<(NEDGE + 255) / 256, 256, 0, stream>>>(eidx, ew, cur, ccol, cw);

  k_bgemm_dual<<<dim3(32, 16), 512, 0, stream>>>(Hb, WmB, bself, HM, HS);
  k_agg2<<<NN, 256, 0, stream>>>(rs, ccol, cw, dis, HM, HS, bmsg, HF);
  k_bgemm3<<<512, 256, 0, stream>>>(HF, WzB, bz, flag, d_out);
}

// Round 7
// 187.991 us; speedup vs baseline: 1.1596x; 1.1596x over previous
//
#include <hip/hip_runtime.h>
#include <hip/hip_bf16.h>
#include <stdint.h>

#define NN 8192
#define GG 512
#define HH 512
#define LL 64
#define TOPK 9                 // K+1 = 9 (incl. self, self weight zeroed)
#define GRES 32                // spatial grid resolution (cell = 1/32)
#define NCELL (GRES*GRES)
#define BPAD 516               // LDS B-panel row pad: 258 dwords == 2 mod 32 (conflict-free class)
#define ELLW 128               // ELL row width: 9 out-edges + in-edges (2D k=9 max in-deg ~54)

typedef unsigned long long u64;
typedef unsigned int u32;
typedef unsigned short u16;

using bf16x8 = __attribute__((ext_vector_type(8))) short;
using f32x4  = __attribute__((ext_vector_type(4))) float;

struct InPtrs { const void* p[12]; };

__device__ __forceinline__ float bf2f(u16 u) { return __uint_as_float(((u32)u) << 16); }
__device__ __forceinline__ u16 f2bf(float f) {
  u32 x = __float_as_uint(f);
  u32 r = x + 0x7fffu + ((x >> 16) & 1u);   // RNE
  return (u16)(r >> 16);
}

// ---------------- inline dtype detection (wave 0 samples 64 u16s of coords) ----------------
__device__ __forceinline__ int detect_isbf(const void* coords_raw, int tid, int* sh) {
  if (tid < 64) {
    float v = bf2f(((const u16*)coords_raw)[tid]);
    bool bad = !(v >= -0.01f && v <= 1.02f);
    u64 bb = __ballot(bad);
    if (tid == 0) *sh = (bb == 0ULL) ? 1 : 0;
  }
  __syncthreads();
  return *sh;
}

// ---------------- convert: small f32 tensors + VECTORIZED big weights + gene ----------------
// Also zeroes deg and inits ELL cursor cur[i]=TOPK (slots 0..8 reserved for out-edges).
__global__ void k_conv_small(InPtrs in, int* __restrict__ flag,
                             float* __restrict__ f32blk, u16* __restrict__ bfblk,
                             float* __restrict__ deg, int* __restrict__ cur,
                             float* __restrict__ sq, u32* __restrict__ geneB) {
  __shared__ int sh;
  int tid = threadIdx.x;
  int isbf = detect_isbf(in.p[1], tid, &sh);
  int gtid = blockIdx.x * blockDim.x + tid;
  int gsz = gridDim.x * blockDim.x;
  if (gtid == 0) *flag = isbf;
  if (gtid < NN) {
    deg[gtid] = 0.0f;
    float x, y;
    if (isbf) { x = bf2f(((const u16*)in.p[1])[2 * gtid]); y = bf2f(((const u16*)in.p[1])[2 * gtid + 1]); }
    else      { x = ((const float*)in.p[1])[2 * gtid];     y = ((const float*)in.p[1])[2 * gtid + 1]; }
    sq[gtid] = __fadd_rn(__fmul_rn(x, x), __fmul_rn(y, y));
  } else if (gtid < 2 * NN) {
    cur[gtid - NN] = TOPK;
  }

  // small f32-dest tensors (both worlds): coords, b_g1, W_c1, b_c1, b_msg, b_self, b_z
  {
    const int scnt[7] = {16384, 512, 1024, 512, 512, 512, 64};
    const int sidx[7] = {1, 3, 4, 5, 7, 9, 11};
    const int sdof[7] = {0, 16384, 16896, 17920, 18432, 18944, 19456};
    for (int e = gtid; e < 19520; e += gsz) {
      int base = 0;
#pragma unroll
      for (int s = 0; s < 7; ++s) {
        if (e < base + scnt[s]) {
          int loc = e - base;
          const void* src = in.p[sidx[s]];
          f32blk[sdof[s] + loc] = isbf ? bf2f(((const u16*)src)[loc]) : ((const float*)src)[loc];
          break;
        }
        base += scnt[s];
      }
    }
  }

  if (!isbf) {
    // big weights f32 -> bf16: Wg(262144), Wm(262144), Ws(262144), Wz(32768) = 204800 float4s
    for (int v = gtid; v < 204800; v += gsz) {
      const float4* sp; u16* dp; int loc;
      if (v < 65536)       { sp = (const float4*)in.p[2];  dp = bfblk;          loc = v; }
      else if (v < 131072) { sp = (const float4*)in.p[6];  dp = bfblk + 262144; loc = v - 65536; }
      else if (v < 196608) { sp = (const float4*)in.p[8];  dp = bfblk + 524288; loc = v - 131072; }
      else                 { sp = (const float4*)in.p[10]; dp = bfblk + 786432; loc = v - 196608; }
      float4 f = sp[loc];
      u64 pk = (u64)f2bf(f.x) | ((u64)f2bf(f.y) << 16) | ((u64)f2bf(f.z) << 32) | ((u64)f2bf(f.w) << 48);
      *(u64*)(dp + 4 * loc) = pk;
    }
    // gene f32 -> bf16: 1048576 float4s
    const float4* g4 = (const float4*)in.p[0];
    u64* gd = (u64*)geneB;
    for (int v = gtid; v < NN * GG / 4; v += gsz) {
      float4 f = g4[v];
      gd[v] = (u64)f2bf(f.x) | ((u64)f2bf(f.y) << 16) | ((u64)f2bf(f.z) << 32) | ((u64)f2bf(f.w) << 48);
    }
  } else {
    // bf16 passthrough copies: 102400 uint4 chunks (gene copy skipped; bgemm0 reads raw)
    for (int v = gtid; v < 102400; v += gsz) {
      const uint4* sp; uint4* dp; int loc;
      if (v < 32768)      { sp = (const uint4*)in.p[2];  dp = (uint4*)bfblk;            loc = v; }
      else if (v < 65536) { sp = (const uint4*)in.p[6];  dp = (uint4*)(bfblk + 262144); loc = v - 32768; }
      else if (v < 98304) { sp = (const uint4*)in.p[8];  dp = (uint4*)(bfblk + 524288); loc = v - 65536; }
      else                { sp = (const uint4*)in.p[10]; dp = (uint4*)(bfblk + 786432); loc = v - 98304; }
      dp[loc] = sp[loc];
    }
  }
}

__device__ __forceinline__ int cell_of(float v) {
  int c = (int)(v * (float)GRES);
  return c < 0 ? 0 : (c > GRES - 1 ? GRES - 1 : c);
}

// ---------------- grid histogram + scan + fill (single block; coords stashed in regs) ------
__global__ __launch_bounds__(1024) void k_grid(const float* __restrict__ coords,
                                               int* __restrict__ gstart,
                                               float4* __restrict__ pts) {
  __shared__ int hist[NCELL];
  __shared__ int part[NCELL];
  int t = threadIdx.x;
  hist[t] = 0;
  __syncthreads();
  float xs[8], ys[8]; int cl[8];
#pragma unroll
  for (int q = 0; q < 8; ++q) {
    int i = t + 1024 * q;
    float2 c = ((const float2*)coords)[i];
    xs[q] = c.x; ys[q] = c.y;
    cl[q] = cell_of(c.y) * GRES + cell_of(c.x);
    atomicAdd(&hist[cl[q]], 1);
  }
  __syncthreads();
  int v = hist[t];
  part[t] = v;
  __syncthreads();
  for (int o = 1; o < NCELL; o <<= 1) {
    int add = 0;
    if (t >= o) add = part[t - o];
    __syncthreads();
    part[t] += add;
    __syncthreads();
  }
  int excl = part[t] - v;
  gstart[t] = excl;
  hist[t] = excl;                 // reuse hist as the fill cursor (LDS atomics)
  if (t == NCELL - 1) gstart[NCELL] = part[t];
  __syncthreads();
#pragma unroll
  for (int q = 0; q < 8; ++q) {
    int i = t + 1024 * q;
    int p = atomicAdd(&hist[cl[q]], 1);
    // z = x*x + y*y with the SAME rounding sequence conv_small used for sq[i] -> bit-identical
    float z = __fadd_rn(__fmul_rn(xs[q], xs[q]), __fmul_rn(ys[q], ys[q]));
    pts[p] = make_float4(xs[q], ys[q], z, __int_as_float(i));
  }
}

// ---------------- KNN top-9: adaptive window, EXACT u64 keys, DIRECT ELL emission ----------
// ELL layout: row i = slots [i*ELLW, i*ELLW+cur[i]); slots 0..8 = out-edges (written here,
// no atomics), slots 9.. = reverse edges appended via atomicAdd(cur[j]). Same double-entry
// symmetrization semantics as the old CSR (both directions carry 0.5*w; mutual pairs sum).
// Comparator stays EXACT (round-4 lesson: truncated comparators swap rank-9 neighbors).
__device__ __forceinline__ float knn_pass(const float4* __restrict__ pts,
                                          const int* __restrict__ gstart,
                                          int x0, int x1, int y0, int y1,
                                          float qx, float qy, float sqi, int lane,
                                          u64 (&karr)[TOPK]) {
  u64 a0 = ~0ULL, a1 = ~0ULL, a2 = ~0ULL, a3 = ~0ULL, a4 = ~0ULL,
      a5 = ~0ULL, a6 = ~0ULL, a7 = ~0ULL, a8 = ~0ULL;
#define KSTEP(A) { u64 t_ = A; bool p_ = x < t_; A = p_ ? x : t_; x = p_ ? t_ : x; }
  for (int yy = y0; yy <= y1; ++yy) {
    int sbeg = gstart[yy * GRES + x0];
    int send = gstart[yy * GRES + x1 + 1];
    for (int p = sbeg + lane; p < send; p += 64) {
      float4 pt = pts[p];
      float dot = __fmaf_rn(qy, pt.y, __fmul_rn(qx, pt.x));
      float d2  = fmaxf(__fsub_rn(__fadd_rn(sqi, pt.z), __fmul_rn(2.0f, dot)), 0.0f);
      u64 x = ((u64)__float_as_uint(d2) << 32) | (u32)__float_as_int(pt.w);
      KSTEP(a0) KSTEP(a1) KSTEP(a2) KSTEP(a3) KSTEP(a4)
      KSTEP(a5) KSTEP(a6) KSTEP(a7) KSTEP(a8)
    }
  }
#undef KSTEP
#pragma unroll
  for (int r = 0; r < TOPK; ++r) {
    u64 g = a0;
#pragma unroll
    for (int o = 32; o > 0; o >>= 1) {
      u64 other = __shfl_xor(g, o, 64);
      if (other < g) g = other;
    }
    bool own = (a0 == g);
    a0 = own ? a1 : a0;  a1 = own ? a2 : a1;  a2 = own ? a3 : a2;
    a3 = own ? a4 : a3;  a4 = own ? a5 : a4;  a5 = own ? a6 : a5;
    a6 = own ? a7 : a6;  a7 = own ? a8 : a7;  a8 = own ? ~0ULL : a8;
    karr[r] = g;
  }
  return __uint_as_float((u32)(karr[TOPK - 1] >> 32));
}

__global__ __launch_bounds__(256) void k_knn_grid(const float4* __restrict__ pts,
                                                  const int* __restrict__ gstart,
                                                  const float* __restrict__ coords,
                                                  const float* __restrict__ sq,
                                                  int* __restrict__ ecol, float* __restrict__ ecw,
                                                  int* __restrict__ cur, float* __restrict__ deg) {
  const int w = threadIdx.x >> 6, lane = threadIdx.x & 63;
  const int i = blockIdx.x * 4 + w;
  const float qx = coords[2 * i], qy = coords[2 * i + 1];
  const float sqi = sq[i];
  const int cx = cell_of(qx), cy = cell_of(qy);

  u64 karr[TOPK];
  float d9 = knn_pass(pts, gstart, max(cx - 1, 0), min(cx + 1, GRES - 1),
                      max(cy - 1, 0), min(cy + 1, GRES - 1), qx, qy, sqi, lane, karr);
  if (!(d9 < 0.00097f)) {                       // h^2 = 0.0009766, 0.7% margin
    d9 = knn_pass(pts, gstart, max(cx - 2, 0), min(cx + 2, GRES - 1),
                  max(cy - 2, 0), min(cy + 2, GRES - 1), qx, qy, sqi, lane, karr);
    if (!(d9 < 0.0038937f))                     // (2h)^2 = 0.0039063
      knn_pass(pts, gstart, 0, GRES - 1, 0, GRES - 1, qx, qy, sqi, lane, karr);
  }

  // direct ELL emission: lanes 0..8 (karr is wave-uniform; compile-time-index select)
  if (lane < TOPK) {
    u64 g = karr[0];
#pragma unroll
    for (int r = 1; r < TOPK; ++r) g = (lane == r) ? karr[r] : g;
    int j = (int)(g & 0xffffffffu);
    float d2 = __uint_as_float((u32)(g >> 32));
    float wgt = (j == i) ? 0.0f : expf(-0.5f * d2);
    float h = 0.5f * wgt;
    ecol[i * ELLW + lane] = j;
    ecw [i * ELLW + lane] = h;
    atomicAdd(&deg[i], h);
    if (j != i) {
      int s = atomicAdd(&cur[j], 1);
      if (s < ELLW) { ecol[j * ELLW + s] = i; ecw[j * ELLW + s] = h; }
      atomicAdd(&deg[j], h);
    }
  }
}

// ====================================================================================
// B-stationary barrier-free MFMA GEMMs (round-2 notes) + XCD-aware block swizzle:
// each XCD (id&7) owns a contiguous row-block group, so the A panel it re-streams
// once per column-panel stays resident in its private 4MB L2 (working set 1-2 MB)
// instead of re-fetching from L3/HBM (64-128 MB of restream traffic).
// ====================================================================================

// ---- GEMM1: h = relu(gene@Wg^T + b) + relu(coords-MLP).  512 thr, BM=128, grid (64,8) ----
__global__ __launch_bounds__(512, 4) void k_bgemm0(const void* __restrict__ Araw,
                                                   const u16* __restrict__ Aconv,
                                                   const u16* __restrict__ W,
                                                   const float* __restrict__ bias,
                                                   const float* __restrict__ coords,
                                                   const float* __restrict__ Wc1,
                                                   const float* __restrict__ bc1,
                                                   const int* __restrict__ flag,
                                                   u16* __restrict__ outp) {
  __shared__ u16 Bs[64][BPAD];
  const int tid = threadIdx.x, lane = tid & 63, w = tid >> 6;
  const int quad = lane >> 4, l16 = lane & 15;
  // XCD swizzle: lin in [0,512); xcd owns 8 row-blocks x 8 col-blocks (A set 1MB -> L2)
  const int lin = blockIdx.x + blockIdx.y * 64;
  const int xcd = lin & 7, slot = lin >> 3;
  const int row0 = (xcd * 8 + (slot & 7)) * 128, col0 = (slot >> 3) * 64;
  int flg = *flag;
  const u16* A = flg ? (const u16*)Araw : Aconv;

  // stage B panel: 64 rows x 64 chunks of 8 u16
#pragma unroll
  for (int q = 0; q < 8; ++q) {
    int idx = tid + 512 * q;
    int r = idx >> 6, c = idx & 63;
    *(uint4*)(&Bs[r][c * 8]) = *(const uint4*)(W + (size_t)(col0 + r) * 512 + c * 8);
  }
  __syncthreads();

  f32x4 acc[4];
#pragma unroll
  for (int n = 0; n < 4; ++n) acc[n] = (f32x4){0.f, 0.f, 0.f, 0.f};

  const u16* Ab = A + (size_t)(row0 + w * 16 + l16) * 512 + quad * 8;
#pragma unroll
  for (int kc = 0; kc < 16; ++kc) {
    bf16x8 af = *(const bf16x8*)(Ab + kc * 32);
    bf16x8 bfr[4];
#pragma unroll
    for (int n = 0; n < 4; ++n)
      bfr[n] = *(const bf16x8*)(&Bs[n * 16 + l16][kc * 32 + quad * 8]);
#pragma unroll
    for (int n = 0; n < 4; ++n)
      acc[n] = __builtin_amdgcn_mfma_f32_16x16x32_bf16(af, bfr[n], acc[n], 0, 0, 0);
  }

  __syncthreads();                 // all waves done reading Bs -> reuse as staging tile
  u16* St = &Bs[0][0];             // [128][64]
  {
    int rloc = w * 16 + quad * 4;
    int rbase = row0 + rloc;
    float cx[4], cy[4];
#pragma unroll
    for (int reg = 0; reg < 4; ++reg) { cx[reg] = coords[2 * (rbase + reg)]; cy[reg] = coords[2 * (rbase + reg) + 1]; }
#pragma unroll
    for (int n = 0; n < 4; ++n) {
      int cg = col0 + n * 16 + l16;
      float bval = bias[cg];
      float wc0 = Wc1[2 * cg], wc1 = Wc1[2 * cg + 1], bcv = bc1[cg];
#pragma unroll
      for (int reg = 0; reg < 4; ++reg) {
        float v = acc[n][reg] + bval;
        float hc = cx[reg] * wc0 + cy[reg] * wc1 + bcv;
        v = fmaxf(v, 0.f) + fmaxf(hc, 0.f);
        St[(rloc + reg) * 64 + n * 16 + l16] = f2bf(v);
      }
    }
  }
  __syncthreads();
#pragma unroll
  for (int q = 0; q < 2; ++q) {
    int idx = tid + 512 * q;
    int r = idx >> 3, c = idx & 7;
    *(uint4*)(outp + (size_t)(row0 + r) * 512 + col0 + c * 8) = ((const uint4*)St)[idx];
  }
}

// ---- dual GEMM: hm = h@Wm^T (raw), hs = relu(h@Ws^T + b_self). Wcat = [Wm;Ws] 1024 rows ----
__global__ __launch_bounds__(512, 4) void k_bgemm_dual(const u16* __restrict__ A,
                                                       const u16* __restrict__ Wcat,
                                                       const float* __restrict__ bself,
                                                       u16* __restrict__ hm,
                                                       u16* __restrict__ hs) {
  __shared__ u16 Bs[64][BPAD];
  const int tid = threadIdx.x, lane = tid & 63, w = tid >> 6;
  const int quad = lane >> 4, l16 = lane & 15;
  // XCD swizzle: lin in [0,512); xcd owns 4 row-blocks x 16 col-blocks (A set 1MB -> L2)
  const int lin = blockIdx.x + blockIdx.y * 32;
  const int xcd = lin & 7, slot = lin >> 3;
  const int row0 = (xcd * 4 + (slot & 3)) * 256, col0 = (slot >> 2) * 64;  // col0 in [0,1024)
  const int selfhalf = (col0 >= 512);

#pragma unroll
  for (int q = 0; q < 8; ++q) {
    int idx = tid + 512 * q;
    int r = idx >> 6, c = idx & 63;
    *(uint4*)(&Bs[r][c * 8]) = *(const uint4*)(Wcat + (size_t)(col0 + r) * 512 + c * 8);
  }
  __syncthreads();

  f32x4 acc[2][4];
#pragma unroll
  for (int mr = 0; mr < 2; ++mr)
#pragma unroll
    for (int n = 0; n < 4; ++n) acc[mr][n] = (f32x4){0.f, 0.f, 0.f, 0.f};

  const u16* Ab = A + (size_t)(row0 + w * 32 + l16) * 512 + quad * 8;
#pragma unroll
  for (int kc = 0; kc < 16; ++kc) {
    bf16x8 af0 = *(const bf16x8*)(Ab + kc * 32);
    bf16x8 af1 = *(const bf16x8*)(Ab + 16 * 512 + kc * 32);
    bf16x8 bfr[4];
#pragma unroll
    for (int n = 0; n < 4; ++n)
      bfr[n] = *(const bf16x8*)(&Bs[n * 16 + l16][kc * 32 + quad * 8]);
#pragma unroll
    for (int n = 0; n < 4; ++n) {
      acc[0][n] = __builtin_amdgcn_mfma_f32_16x16x32_bf16(af0, bfr[n], acc[0][n], 0, 0, 0);
      acc[1][n] = __builtin_amdgcn_mfma_f32_16x16x32_bf16(af1, bfr[n], acc[1][n], 0, 0, 0);
    }
  }

  __syncthreads();
  u16* St = &Bs[0][0];             // [256][64]
  const int dcol0 = col0 & 511;
#pragma unroll
  for (int mr = 0; mr < 2; ++mr) {
    int rloc = w * 32 + mr * 16 + quad * 4;
#pragma unroll
    for (int n = 0; n < 4; ++n) {
      int cl = dcol0 + n * 16 + l16;
      float bval = selfhalf ? bself[cl] : 0.f;
#pragma unroll
      for (int reg = 0; reg < 4; ++reg) {
        float v = acc[mr][n][reg];
        if (selfhalf) v = fmaxf(v + bval, 0.f);   // hs = relu(h@Ws^T + b_self)
        St[(rloc + reg) * 64 + n * 16 + l16] = f2bf(v);  // hm raw: bias added post-agg
      }
    }
  }
  __syncthreads();
  u16* dst = selfhalf ? hs : hm;
#pragma unroll
  for (int q = 0; q < 4; ++q) {
    int idx = tid + 512 * q;
    int r = idx >> 3, c = idx & 7;
    *(uint4*)(dst + (size_t)(row0 + r) * 512 + dcol0 + c * 8) = ((const uint4*)St)[idx];
  }
}

// ---- h_final = relu(relu(A_norm@hm + b_msg) + hs)  (ELL SpMV, 4-edge-wide gather) ----
// dis computed on the fly with the bit-identical 1.0f/sqrtf(deg+1e-8f) expression the
// old k_scan used (k_scan + k_fill + dis/rs/cur-CSR arrays all eliminated).
__global__ __launch_bounds__(256) void k_agg2(const int* __restrict__ cur, const int* __restrict__ ecol,
                                              const float* __restrict__ ecw, const float* __restrict__ deg,
                                              const u16* __restrict__ hm, const u16* __restrict__ hs,
                                              const float* __restrict__ bmsg, u16* __restrict__ hf) {
  __shared__ float sacc[4][512];
  const int i = blockIdx.x, t = threadIdx.x;
  const int g = t >> 6, l = t & 63;
  const int b = i * ELLW;
  const int e = b + min(cur[i], ELLW);
  float acc[8];
#pragma unroll
  for (int j = 0; j < 8; ++j) acc[j] = 0.f;
  for (int q = b + g; q < e; q += 4) {
    int c = ecol[q];
    float w = ecw[q] * (1.0f / sqrtf(deg[c] + 1e-8f));
    uint4 p = *(const uint4*)(hm + (size_t)c * HH + l * 8);
    acc[0] = fmaf(w, bf2f((u16)(p.x & 0xffff)), acc[0]);
    acc[1] = fmaf(w, bf2f((u16)(p.x >> 16)),    acc[1]);
    acc[2] = fmaf(w, bf2f((u16)(p.y & 0xffff)), acc[2]);
    acc[3] = fmaf(w, bf2f((u16)(p.y >> 16)),    acc[3]);
    acc[4] = fmaf(w, bf2f((u16)(p.z & 0xffff)), acc[4]);
    acc[5] = fmaf(w, bf2f((u16)(p.z >> 16)),    acc[5]);
    acc[6] = fmaf(w, bf2f((u16)(p.w & 0xffff)), acc[6]);
    acc[7] = fmaf(w, bf2f((u16)(p.w >> 16)),    acc[7]);
  }
#pragma unroll
  for (int j = 0; j < 8; ++j) sacc[g][l * 8 + j] = acc[j];
  __syncthreads();
  float di = 1.0f / sqrtf(deg[i] + 1e-8f);
  int c0 = 2 * t, c1 = 2 * t + 1;
  float s0 = (sacc[0][c0] + sacc[1][c0]) + (sacc[2][c0] + sacc[3][c0]);
  float s1 = (sacc[0][c1] + sacc[1][c1]) + (sacc[2][c1] + sacc[3][c1]);
  float m0 = fmaxf(fmaf(di, s0, bmsg[c0]), 0.f);
  float m1 = fmaxf(fmaf(di, s1, bmsg[c1]), 0.f);
  u32 sp = *(const u32*)(hs + (size_t)i * HH + c0);
  float f0 = fmaxf(m0 + bf2f((u16)(sp & 0xffff)), 0.f);
  float f1 = fmaxf(m1 + bf2f((u16)(sp >> 16)), 0.f);
  u32 packed = (u32)f2bf(f0) | ((u32)f2bf(f1) << 16);
  *(u32*)(hf + (size_t)i * HH + c0) = packed;
}

// ---- GEMM3: out = h_final@Wz^T + bz.  BM=16, 256 thr, grid 512; LDS-staged stores ----
__global__ __launch_bounds__(256) void k_bgemm3(const u16* __restrict__ A,
                                                const u16* __restrict__ W,
                                                const float* __restrict__ bias,
                                                const int* __restrict__ flag,
                                                void* __restrict__ outp) {
  __shared__ u16 Bs[64][BPAD];
  const int tid = threadIdx.x, lane = tid & 63, w = tid >> 6;   // w = n-frag 0..3
  const int quad = lane >> 4, l16 = lane & 15;
  const int row0 = blockIdx.x * 16;
  int flg = *flag;

#pragma unroll
  for (int q = 0; q < 16; ++q) {
    int idx = tid + 256 * q;
    int r = idx >> 6, c = idx & 63;
    *(uint4*)(&Bs[r][c * 8]) = *(const uint4*)(W + (size_t)r * 512 + c * 8);
  }
  __syncthreads();

  f32x4 acc = (f32x4){0.f, 0.f, 0.f, 0.f};
  const u16* Ab = A + (size_t)(row0 + l16) * 512 + quad * 8;
#pragma unroll
  for (int kc = 0; kc < 16; ++kc) {
    bf16x8 af  = *(const bf16x8*)(Ab + kc * 32);
    bf16x8 bfw = *(const bf16x8*)(&Bs[w * 16 + l16][kc * 32 + quad * 8]);
    acc = __builtin_amdgcn_mfma_f32_16x16x32_bf16(af, bfw, acc, 0, 0, 0);
  }

  __syncthreads();
  if (!flg) {
    // fp32-output world (live path): stage [16][64] f32 tile, float4 stores
    float* Stf = (float*)&Bs[0][0];
    float bval = bias[w * 16 + l16];
#pragma unroll
    for (int reg = 0; reg < 4; ++reg)
      Stf[(quad * 4 + reg) * 64 + w * 16 + l16] = acc[reg] + bval;
    __syncthreads();
    int r = tid >> 4, c = tid & 15;
    ((float4*)outp)[(size_t)(row0 + r) * 16 + c] = ((const float4*)Stf)[tid];
    return;
  }

  u16* St = &Bs[0][0];             // [16][64] bf16
  float bval = bias[w * 16 + l16];
#pragma unroll
  for (int reg = 0; reg < 4; ++reg)
    St[(quad * 4 + reg) * 64 + w * 16 + l16] = f2bf(acc[reg] + bval);
  __syncthreads();
  if (tid < 128) {
    int r = tid >> 3, c = tid & 7;
    *(uint4*)((u16*)outp + (size_t)(row0 + r) * 64 + c * 8) = ((const uint4*)St)[tid];
  }
}

extern "C" void kernel_launch(void* const* d_in, const int* in_sizes, int n_in,
                              void* d_out, int out_size, void* d_ws, size_t ws_size,
                              hipStream_t stream) {
  float* ws = (float*)d_ws;
  size_t off = 0;
  auto alloc = [&](size_t n) { size_t o = off; off += (n + 15) & ~(size_t)15; return o; };

  const size_t PLANE = (size_t)NN * HH / 2;

  size_t o_flag  = alloc(16);
  size_t o_f32   = alloc(19520);
  size_t o_bfw   = alloc(409600);
  size_t o_geneB = alloc(PLANE);
  size_t o_Hb    = alloc(PLANE);
  size_t o_Mb    = alloc(PLANE);
  size_t o_sq    = alloc(NN);
  size_t o_deg   = alloc(NN);
  size_t o_cur   = alloc(NN);
  size_t o_ecol  = alloc((size_t)NN * ELLW);
  size_t o_ecw   = alloc((size_t)NN * ELLW);
  size_t o_pts   = alloc(NN * 4);
  size_t o_gsta  = alloc(NCELL + 16);
  (void)ws_size;

  int*   flag    = (int*)(ws + o_flag);
  float* f32blk  = ws + o_f32;
  float* coordsF = f32blk + 0;
  float* bg1     = f32blk + 16384;
  float* Wc1f    = f32blk + 16896;
  float* bc1f    = f32blk + 17920;
  float* bmsg    = f32blk + 18432;
  float* bself   = f32blk + 18944;
  float* bz      = f32blk + 19456;
  u16*   bfblk   = (u16*)(ws + o_bfw);
  u16*   WgB     = bfblk + 0;
  u16*   WmB     = bfblk + 262144;   // [Wm;Ws] contiguous 1024x512 starting here
  u16*   WzB     = bfblk + 786432;
  u16*   geneB   = (u16*)(ws + o_geneB);
  u16*   Hb      = (u16*)(ws + o_Hb);
  u16*   Mb      = (u16*)(ws + o_Mb);
  float* sq      = ws + o_sq;
  float* deg     = ws + o_deg;
  int*   cur     = (int*)(ws + o_cur);
  int*   ecol    = (int*)(ws + o_ecol);
  float* ecw     = ws + o_ecw;
  float4* pts    = (float4*)(ws + o_pts);
  int*   gstart  = (int*)(ws + o_gsta);

  // plane reuse: hm <- geneB plane; hs <- Mb plane; h_final <- Hb plane.
  u16* HM = geneB;
  u16* HS = Mb;
  u16* HF = Hb;

  InPtrs ip;
  for (int s = 0; s < 12; ++s) ip.p[s] = d_in[s];

  k_conv_small<<<512, 256, 0, stream>>>(ip, flag, f32blk, bfblk, deg, cur, sq, (u32*)geneB);
  k_bgemm0<<<dim3(64, 8), 512, 0, stream>>>(d_in[0], geneB, WgB, bg1, coordsF, Wc1f, bc1f, flag, Hb);
  k_grid<<<1, 1024, 0, stream>>>(coordsF, gstart, pts);
  k_knn_grid<<<NN / 4, 256, 0, stream>>>(pts, gstart, coordsF, sq, ecol, ecw, cur, deg);
  k_bgemm_dual<<<dim3(32, 16), 512, 0, stream>>>(Hb, WmB, bself, HM, HS);
  k_agg2<<<NN, 256, 0, stream>>>(cur, ecol, ecw, deg, HM, HS, bmsg, HF);
  k_bgemm3<<<512, 256, 0, stream>>>(HF, WzB, bz, flag, d_out);
}